// Round 9
// baseline (176.497 us; speedup 1.0000x reference)
//
#include <hip/hip_runtime.h>

#define NB  32
#define NLQ 64
#define NLV 128
#define NQS 512
#define NFS 1024
#define NBN 512
#define CC  2.8853900817779268f   // 2*log2(e):  exp(2x) = exp2(CC*x)

typedef float  floatx4 __attribute__((ext_vector_type(4)));
typedef __bf16 bf16x8  __attribute__((ext_vector_type(8)));
typedef unsigned short us;

__device__ __forceinline__ us f2bf(float f) {
    unsigned int u = __float_as_uint(f);
    u += 0x7fffu + ((u >> 16) & 1u);   // round-to-nearest-even
    return (us)(u >> 16);
}
// truncating pack of two fp32 -> packed bf16x2, one v_perm_b32
__device__ __forceinline__ unsigned int pktrunc(float lo, float hi) {
    return __builtin_amdgcn_perm(__float_as_uint(hi), __float_as_uint(lo), 0x07060302u);
}
__device__ __forceinline__ float blo(unsigned int u) {
    return __uint_as_float(u << 16);
}
__device__ __forceinline__ float bhi(unsigned int u) {
    return __uint_as_float(u & 0xffff0000u);
}

// ---------------- convert: fp32 -> bf16 (phr,vis,W,U); also writes sgf[:, :512]=phr
#define PHR4 262144
#define VIS4 1048576
#define WW4  65536
#define UU4  131072
#define TOT4 (PHR4 + VIS4 + WW4 + UU4)   // 1,507,328 float4s

__global__ __launch_bounds__(256) void convert_bf16(
    const float* __restrict__ phr, const float* __restrict__ vis,
    const float* __restrict__ W,   const float* __restrict__ U,
    us* __restrict__ phr_b, us* __restrict__ vis_b,
    us* __restrict__ W_b,   us* __restrict__ U_b,
    float* __restrict__ out_sgf)
{
    int i = blockIdx.x * 256 + threadIdx.x;
    if (i >= TOT4) return;
    const float* src; us* dst; int o;
    if (i < PHR4)              { src = phr; dst = phr_b; o = i; }
    else if (i < PHR4 + VIS4)  { src = vis; dst = vis_b; o = i - PHR4; }
    else if (i < PHR4 + VIS4 + WW4) { src = W; dst = W_b; o = i - PHR4 - VIS4; }
    else                       { src = U; dst = U_b; o = i - PHR4 - VIS4 - WW4; }
    float4 v = ((const float4*)src)[o];
    uint2 r = { pktrunc(v.x, v.y), pktrunc(v.z, v.w) };
    *(uint2*)(dst + (size_t)o * 4) = r;
    if (i < PHR4) {   // concat left half: sgf[row, 0:512] = phr (fp32, exact)
        int row = o >> 7, c4 = o & 127;
        ((float4*)out_sgf)[(size_t)row * 384 + c4] = v;
    }
}

// ---------------- GEMM: 128x128 tile, bf16 in, depth-2 reg prefetch ---------
// Epilogue: Y = exp2(CC*(acc[+bias])) stored bf16 (tanh product trick).
__device__ __forceinline__ void gemm128(
    us* As, us* Bs,                       // [128*40] each
    const us* __restrict__ A, const us* __restrict__ Bt,
    const float* __restrict__ bias, us* __restrict__ C,
    int K, int bx, int by, int hasb)
{
    const int tid  = threadIdx.x;
    const int m0   = bx * 128;
    const int n0   = by * 128;
    const int wave = tid >> 6;
    const int lane = tid & 63;
    const int wm   = (wave >> 1) * 64;
    const int wn   = (wave & 1) * 64;
    const int srow = tid >> 1;          // 0..127
    const int skk  = (tid & 1) * 16;    // 0 or 16 (elements)
    const int fm   = lane & 15;
    const int fko  = (lane >> 4) * 8;

    floatx4 acc[4][4] = {};
    const us* ag = A  + (size_t)(m0 + srow) * K + skk;
    const us* bg = Bt + (size_t)(n0 + srow) * K + skk;

    // two K-tiles in flight
    uint4 pa[2][2], pb[2][2];
    pa[0][0] = *(const uint4*)(ag);      pa[0][1] = *(const uint4*)(ag + 8);
    pb[0][0] = *(const uint4*)(bg);      pb[0][1] = *(const uint4*)(bg + 8);
    pa[1][0] = *(const uint4*)(ag + 32); pa[1][1] = *(const uint4*)(ag + 40);
    pb[1][0] = *(const uint4*)(bg + 32); pb[1][1] = *(const uint4*)(bg + 40);

    int buf = 0;
    for (int k0 = 0; k0 < K; k0 += 32, buf ^= 1) {
        __syncthreads();
        *(uint4*)(As + srow * 40 + skk)     = pa[buf][0];
        *(uint4*)(As + srow * 40 + skk + 8) = pa[buf][1];
        *(uint4*)(Bs + srow * 40 + skk)     = pb[buf][0];
        *(uint4*)(Bs + srow * 40 + skk + 8) = pb[buf][1];
        const int kn = k0 + 64;
        if (kn < K) {   // refill the buffer just staged (consumed 2 iters later)
            pa[buf][0] = *(const uint4*)(ag + kn);
            pa[buf][1] = *(const uint4*)(ag + kn + 8);
            pb[buf][0] = *(const uint4*)(bg + kn);
            pb[buf][1] = *(const uint4*)(bg + kn + 8);
        }
        __syncthreads();
        bf16x8 am[4], bn[4];
        #pragma unroll
        for (int i = 0; i < 4; ++i)
            am[i] = *(const bf16x8*)(As + (wm + 16 * i + fm) * 40 + fko);
        #pragma unroll
        for (int j = 0; j < 4; ++j)
            bn[j] = *(const bf16x8*)(Bs + (wn + 16 * j + fm) * 40 + fko);
        #pragma unroll
        for (int i = 0; i < 4; ++i)
            #pragma unroll
            for (int j = 0; j < 4; ++j)
                acc[i][j] = __builtin_amdgcn_mfma_f32_16x16x32_bf16(am[i], bn[j], acc[i][j], 0, 0, 0);
    }

    // C/D layout: col = lane&15, row = (lane>>4)*4 + reg
    const int cr = (lane >> 4) * 4;
    const int cc = lane & 15;
    #pragma unroll
    for (int i = 0; i < 4; ++i)
        #pragma unroll
        for (int j = 0; j < 4; ++j)
            #pragma unroll
            for (int r = 0; r < 4; ++r) {
                int gm = m0 + wm + 16 * i + cr + r;
                int gn = n0 + wn + 16 * j + cc;
                float v = acc[i][j][r];
                if (hasb) v += bias[gn];
                C[(size_t)gm * NBN + gn] = f2bf(__builtin_amdgcn_exp2f(CC * v));
            }
}

// blocks 0..63: Yq=exp2(CC*(phr@W^T+b)) (M=2048,K=512, nbx=16)
// blocks 64..191: Yv=exp2(CC*(vis@U^T)) (M=4096,K=1024, nbx=32)
// bx = blk % nbx with 8|nbx  ->  same-bx blocks share an XCD (A-row L2 reuse)
__global__ __launch_bounds__(256) void gemm_both(
    const us* __restrict__ phr_b, const us* __restrict__ W_b,
    const float* __restrict__ bias,
    const us* __restrict__ vis_b, const us* __restrict__ U_b,
    us* __restrict__ whY, us* __restrict__ uvY)
{
    __shared__ __align__(16) us As[128 * 40];
    __shared__ __align__(16) us Bs[128 * 40];
    int blk = blockIdx.x;
    if (blk < 64) {
        gemm128(As, Bs, phr_b, W_b, bias, whY, NQS, blk % 16, blk / 16, 1);
    } else {
        blk -= 64;
        gemm128(As, Bs, vis_b, U_b, bias, uvY, NFS, blk % 32, blk / 32, 0);
    }
}

// ---------------- energies + softmax ---------------------------------------
// blk = q*32 + b.  tanh(x) = 1 - 2/(1 + Yq[n]*Yv[n]).
__global__ __launch_bounds__(256) void energize(
    const us* __restrict__ whY,   // [2048,512] bf16
    const us* __restrict__ uvY,   // [4096,512] bf16
    const float* __restrict__ wvec,
    float* __restrict__ p_ws, float* __restrict__ out_w, float* __restrict__ out_e)
{
    const float LOG2E = 1.4426950408889634f;
    const int blk  = blockIdx.x;
    const int q    = blk >> 5;
    const int b    = blk & 31;
    const int row  = b * NLQ + q;
    const int tid  = threadIdx.x;
    const int wave = tid >> 6;
    const int lane = tid & 63;

    __shared__ float e_s[128];

    const int n0 = lane << 3;
    uint4 yq4 = *(const uint4*)(whY + (size_t)row * NBN + n0);
    float Yq[8] = { blo(yq4.x), bhi(yq4.x), blo(yq4.y), bhi(yq4.y),
                    blo(yq4.z), bhi(yq4.z), blo(yq4.w), bhi(yq4.w) };
    float4 w0 = *(const float4*)(wvec + n0);
    float4 w1 = *(const float4*)(wvec + n0 + 4);
    float nw2[8] = { 2.f*w0.x, 2.f*w0.y, 2.f*w0.z, 2.f*w0.w,
                     2.f*w1.x, 2.f*w1.y, 2.f*w1.z, 2.f*w1.w };
    float sumw = w0.x + w0.y + w0.z + w0.w + w1.x + w1.y + w1.z + w1.w;
    #pragma unroll
    for (int off = 32; off; off >>= 1) sumw += __shfl_xor(sumw, off);

    #pragma unroll
    for (int vblk = 0; vblk < 4; ++vblk) {
        const us* base = uvY + ((size_t)b * NLV + wave * 32 + vblk * 8) * NBN + n0;
        float s[8];
        #pragma unroll
        for (int j = 0; j < 8; ++j) {
            uint4 u = *(const uint4*)(base + (size_t)j * NBN);
            float acc = 0.f;
            auto term = [&](unsigned int uu, int k) {
                float d0 = fmaf(blo(uu), Yq[k],     1.f);
                float d1 = fmaf(bhi(uu), Yq[k + 1], 1.f);
                acc = fmaf(nw2[k],     __builtin_amdgcn_rcpf(d0), acc);
                acc = fmaf(nw2[k + 1], __builtin_amdgcn_rcpf(d1), acc);
            };
            term(u.x, 0); term(u.y, 2); term(u.z, 4); term(u.w, 6);
            s[j] = acc;
        }
        // uniform reduce over lane-bits 3,4,5 (ILP across 8 accumulators)
        #pragma unroll
        for (int m = 8; m <= 32; m <<= 1)
            #pragma unroll
            for (int j = 0; j < 8; ++j) s[j] += __shfl_xor(s[j], m);
        // reduce-scatter over lane-bits 0,1,2
        float t[4];
        #pragma unroll
        for (int p = 0; p < 4; ++p) {
            float ae = s[2*p]     + __shfl_xor(s[2*p],     1);
            float bo = s[2*p + 1] + __shfl_xor(s[2*p + 1], 1);
            t[p] = (lane & 1) ? bo : ae;
        }
        float u2[2];
        #pragma unroll
        for (int p = 0; p < 2; ++p) {
            float ae = t[2*p]     + __shfl_xor(t[2*p],     2);
            float bo = t[2*p + 1] + __shfl_xor(t[2*p + 1], 2);
            u2[p] = (lane & 2) ? bo : ae;
        }
        {
            float ae = u2[0] + __shfl_xor(u2[0], 4);
            float bo = u2[1] + __shfl_xor(u2[1], 4);
            float r  = (lane & 4) ? bo : ae;
            if (lane < 8) e_s[wave * 32 + vblk * 8 + lane] = sumw - r;
        }
    }
    __syncthreads();

    if (wave == 0) {
        float e0 = e_s[lane];
        float e1 = e_s[lane + 64];
        float m = fmaxf(e0, e1);
        #pragma unroll
        for (int off = 32; off; off >>= 1) m = fmaxf(m, __shfl_xor(m, off));
        float x0 = __builtin_amdgcn_exp2f((e0 - m) * LOG2E);
        float x1 = __builtin_amdgcn_exp2f((e1 - m) * LOG2E);
        float ss = x0 + x1;
        #pragma unroll
        for (int off = 32; off; off >>= 1) ss += __shfl_xor(ss, off);
        float inv = __builtin_amdgcn_rcpf(ss);
        float p0 = x0 * inv, p1 = x1 * inv;
        size_t o = (size_t)row * NLV;
        p_ws[o + lane]       = p0;
        p_ws[o + lane + 64]  = p1;
        out_w[o + lane]      = p0;
        out_w[o + lane + 64] = p1;
        out_e[o + lane]      = e0;
        out_e[o + lane + 64] = e1;
    }
}

// ---------------- aligned (bf16 vis) ----------------------------------------
// blk = qg*32 + b (qg: group of 4 q). Thread owns 4 f for 4 q.
__global__ __launch_bounds__(256) void aligned_k(
    const us* __restrict__ vis_b,     // [32,128,1024] bf16
    const float* __restrict__ p_ws,   // [2048,128]
    float* __restrict__ out_sgf)      // [32,64,1536]
{
    const int blk = blockIdx.x;
    const int b   = blk & 31;
    const int qg  = blk >> 5;         // 0..15
    const int tid = threadIdx.x;

    __shared__ float p_s[4][128];
    if (tid < 128) {
        const float* src = p_ws + (size_t)(b * NLQ + qg * 4) * NLV;
        ((float4*)&p_s[0][0])[tid] = ((const float4*)src)[tid];
    }
    __syncthreads();

    const int f0 = tid * 4;
    float4 acc[4] = {};
    const us* vb = vis_b + (size_t)b * NLV * NFS + f0;
    for (int v0 = 0; v0 < NLV; v0 += 4) {
        float4 pv[4];
        #pragma unroll
        for (int qq = 0; qq < 4; ++qq) pv[qq] = *(const float4*)&p_s[qq][v0];
        #pragma unroll
        for (int dv = 0; dv < 4; ++dv) {
            uint2 u = *(const uint2*)(vb + (size_t)(v0 + dv) * NFS);
            float x0 = blo(u.x), x1 = bhi(u.x), x2 = blo(u.y), x3 = bhi(u.y);
            #pragma unroll
            for (int qq = 0; qq < 4; ++qq) {
                float p = (dv == 0) ? pv[qq].x : (dv == 1) ? pv[qq].y
                        : (dv == 2) ? pv[qq].z : pv[qq].w;
                acc[qq].x = fmaf(p, x0, acc[qq].x);
                acc[qq].y = fmaf(p, x1, acc[qq].y);
                acc[qq].z = fmaf(p, x2, acc[qq].z);
                acc[qq].w = fmaf(p, x3, acc[qq].w);
            }
        }
    }
    #pragma unroll
    for (int qq = 0; qq < 4; ++qq) {
        size_t row = (size_t)(b * NLQ + qg * 4 + qq);
        *(float4*)(out_sgf + row * (NQS + NFS) + NQS + f0) = acc[qq];
    }
}

extern "C" void kernel_launch(void* const* d_in, const int* in_sizes, int n_in,
                              void* d_out, int out_size, void* d_ws, size_t ws_size,
                              hipStream_t stream) {
    const float* phr  = (const float*)d_in[0];
    const float* vis  = (const float*)d_in[1];
    const float* W    = (const float*)d_in[2];
    const float* U    = (const float*)d_in[3];
    const float* bias = (const float*)d_in[4];
    const float* wvec = (const float*)d_in[5];

    char* ws = (char*)d_ws;
    us* phr_b = (us*)ws;                                  // 2 MB
    us* vis_b = (us*)(ws + (2u << 20));                   // 8 MB
    us* W_b   = (us*)(ws + (10u << 20));                  // 0.5 MB
    us* U_b   = (us*)(ws + (10u << 20) + (512u << 10));   // 1 MB
    us* whY   = (us*)(ws + (12u << 20));                  // 2 MB
    us* uvY   = (us*)(ws + (14u << 20));                  // 4 MB
    float* p_ws = (float*)(ws + (18u << 20));             // 1 MB

    float* out     = (float*)d_out;
    float* out_sgf = out;
    float* out_w   = out_sgf + (size_t)NB * NLQ * (NQS + NFS);
    float* out_e   = out_w   + (size_t)NB * NLQ * NLV;

    convert_bf16<<<(TOT4 + 255) / 256, 256, 0, stream>>>(
        phr, vis, W, U, phr_b, vis_b, W_b, U_b, out_sgf);
    gemm_both<<<192, 256, 0, stream>>>(phr_b, W_b, bias, vis_b, U_b, whY, uvY);
    energize<<<NB * NLQ, 256, 0, stream>>>(whY, uvY, wvec, p_ws, out_w, out_e);
    aligned_k<<<NB * 16, 256, 0, stream>>>(vis_b, p_ws, out_sgf);
}

// Round 10
// 132.906 us; speedup vs baseline: 1.3280x; 1.3280x over previous
//
#include <hip/hip_runtime.h>

#define NB  32
#define NLQ 64
#define NLV 128
#define NQS 512
#define NFS 1024
#define NBN 512
#define CC  2.8853900817779268f   // 2*log2(e):  exp(2x) = exp2(CC*x)

typedef float  floatx4 __attribute__((ext_vector_type(4)));
typedef __bf16 bf16x8  __attribute__((ext_vector_type(8)));
typedef unsigned short us;

__device__ __forceinline__ us f2bf(float f) {
    unsigned int u = __float_as_uint(f);
    u += 0x7fffu + ((u >> 16) & 1u);   // round-to-nearest-even
    return (us)(u >> 16);
}
// truncating pack of two fp32 -> packed bf16x2, one v_perm_b32
__device__ __forceinline__ unsigned int pktrunc(float lo, float hi) {
    return __builtin_amdgcn_perm(__float_as_uint(hi), __float_as_uint(lo), 0x07060302u);
}
__device__ __forceinline__ float blo(unsigned int u) {
    return __uint_as_float(u << 16);
}
__device__ __forceinline__ float bhi(unsigned int u) {
    return __uint_as_float(u & 0xffff0000u);
}

// ---------------- convert: fp32 -> bf16 (phr,vis,W,U); also writes sgf[:, :512]=phr
#define PHR4 262144
#define VIS4 1048576
#define WW4  65536
#define UU4  131072
#define TOT4 (PHR4 + VIS4 + WW4 + UU4)   // 1,507,328 float4s

__global__ __launch_bounds__(256) void convert_bf16(
    const float* __restrict__ phr, const float* __restrict__ vis,
    const float* __restrict__ W,   const float* __restrict__ U,
    us* __restrict__ phr_b, us* __restrict__ vis_b,
    us* __restrict__ W_b,   us* __restrict__ U_b,
    float* __restrict__ out_sgf)
{
    int i = blockIdx.x * 256 + threadIdx.x;
    if (i >= TOT4) return;
    const float* src; us* dst; int o;
    if (i < PHR4)              { src = phr; dst = phr_b; o = i; }
    else if (i < PHR4 + VIS4)  { src = vis; dst = vis_b; o = i - PHR4; }
    else if (i < PHR4 + VIS4 + WW4) { src = W; dst = W_b; o = i - PHR4 - VIS4; }
    else                       { src = U; dst = U_b; o = i - PHR4 - VIS4 - WW4; }
    float4 v = ((const float4*)src)[o];
    uint2 r = { pktrunc(v.x, v.y), pktrunc(v.z, v.w) };
    *(uint2*)(dst + (size_t)o * 4) = r;
    if (i < PHR4) {   // concat left half: sgf[row, 0:512] = phr (fp32, exact)
        int row = o >> 7, c4 = o & 127;
        ((float4*)out_sgf)[(size_t)row * 384 + c4] = v;
    }
}

// ---------------- GEMM: 64x64 tile, K-tile 32, bf16 in, 4 waves -------------
// Epilogue: Y = exp2(CC*(acc[+bias])) stored bf16 (tanh product trick).
__device__ __forceinline__ void gemm64(
    us* As, us* Bs,                       // [64*40] each
    const us* __restrict__ A, const us* __restrict__ Bt,
    const float* __restrict__ bias, us* __restrict__ C,
    int K, int bx, int by, int hasb)
{
    const int tid  = threadIdx.x;
    const int m0   = bx * 64;
    const int n0   = by * 64;
    const int wave = tid >> 6;
    const int lane = tid & 63;
    const int wm   = (wave >> 1) * 32;
    const int wn   = (wave & 1) * 32;
    const int srow = tid >> 2;          // 0..63
    const int sk   = (tid & 3) * 8;     // k offset (elements): 0,8,16,24
    const int fm   = lane & 15;
    const int fko  = (lane >> 4) * 8;

    floatx4 acc[2][2] = {};
    const us* ag = A  + (size_t)(m0 + srow) * K + sk;
    const us* bg = Bt + (size_t)(n0 + srow) * K + sk;

    uint4 av = *(const uint4*)(ag);
    uint4 bv = *(const uint4*)(bg);

    for (int k0 = 0; k0 < K; k0 += 32) {
        __syncthreads();
        *(uint4*)(As + srow * 40 + sk) = av;
        *(uint4*)(Bs + srow * 40 + sk) = bv;
        const int kn = k0 + 32;
        if (kn < K) {                   // next-tile load; hidden by other blocks
            av = *(const uint4*)(ag + kn);
            bv = *(const uint4*)(bg + kn);
        }
        __syncthreads();
        bf16x8 am[2], bn[2];
        #pragma unroll
        for (int i = 0; i < 2; ++i)
            am[i] = *(const bf16x8*)(As + (wm + 16 * i + fm) * 40 + fko);
        #pragma unroll
        for (int j = 0; j < 2; ++j)
            bn[j] = *(const bf16x8*)(Bs + (wn + 16 * j + fm) * 40 + fko);
        #pragma unroll
        for (int i = 0; i < 2; ++i)
            #pragma unroll
            for (int j = 0; j < 2; ++j)
                acc[i][j] = __builtin_amdgcn_mfma_f32_16x16x32_bf16(am[i], bn[j], acc[i][j], 0, 0, 0);
    }

    // C/D layout: col = lane&15, row = (lane>>4)*4 + reg
    const int cr = (lane >> 4) * 4;
    const int cc = lane & 15;
    #pragma unroll
    for (int i = 0; i < 2; ++i)
        #pragma unroll
        for (int j = 0; j < 2; ++j)
            #pragma unroll
            for (int r = 0; r < 4; ++r) {
                int gm = m0 + wm + 16 * i + cr + r;
                int gn = n0 + wn + 16 * j + cc;
                float v = acc[i][j][r];
                if (hasb) v += bias[gn];
                C[(size_t)gm * NBN + gn] = f2bf(__builtin_amdgcn_exp2f(CC * v));
            }
}

// blocks 0..255: Yq=exp2(CC*(phr@W^T+b)) (M=2048,K=512, nbx=32)
// blocks 256..767: Yv=exp2(CC*(vis@U^T)) (M=4096,K=1024, nbx=64)
// bx = blk % nbx with 8|nbx -> blocks sharing A-rows land on one XCD's L2
__global__ __launch_bounds__(256) void gemm_both(
    const us* __restrict__ phr_b, const us* __restrict__ W_b,
    const float* __restrict__ bias,
    const us* __restrict__ vis_b, const us* __restrict__ U_b,
    us* __restrict__ whY, us* __restrict__ uvY)
{
    __shared__ __align__(16) us As[64 * 40];
    __shared__ __align__(16) us Bs[64 * 40];
    int blk = blockIdx.x;
    if (blk < 256) {
        gemm64(As, Bs, phr_b, W_b, bias, whY, NQS, blk % 32, blk / 32, 1);
    } else {
        blk -= 256;
        gemm64(As, Bs, vis_b, U_b, bias, uvY, NFS, blk % 64, blk / 64, 0);
    }
}

// ---------------- energies + softmax ---------------------------------------
// blk = q*32 + b.  tanh(x) = 1 - 2/(1 + Yq[n]*Yv[n]).
__global__ __launch_bounds__(256) void energize(
    const us* __restrict__ whY,   // [2048,512] bf16
    const us* __restrict__ uvY,   // [4096,512] bf16
    const float* __restrict__ wvec,
    float* __restrict__ p_ws, float* __restrict__ out_w, float* __restrict__ out_e)
{
    const float LOG2E = 1.4426950408889634f;
    const int blk  = blockIdx.x;
    const int q    = blk >> 5;
    const int b    = blk & 31;
    const int row  = b * NLQ + q;
    const int tid  = threadIdx.x;
    const int wave = tid >> 6;
    const int lane = tid & 63;

    __shared__ float e_s[128];

    const int n0 = lane << 3;
    uint4 yq4 = *(const uint4*)(whY + (size_t)row * NBN + n0);
    float Yq[8] = { blo(yq4.x), bhi(yq4.x), blo(yq4.y), bhi(yq4.y),
                    blo(yq4.z), bhi(yq4.z), blo(yq4.w), bhi(yq4.w) };
    float4 w0 = *(const float4*)(wvec + n0);
    float4 w1 = *(const float4*)(wvec + n0 + 4);
    float nw2[8] = { 2.f*w0.x, 2.f*w0.y, 2.f*w0.z, 2.f*w0.w,
                     2.f*w1.x, 2.f*w1.y, 2.f*w1.z, 2.f*w1.w };
    float sumw = w0.x + w0.y + w0.z + w0.w + w1.x + w1.y + w1.z + w1.w;
    #pragma unroll
    for (int off = 32; off; off >>= 1) sumw += __shfl_xor(sumw, off);

    #pragma unroll
    for (int vblk = 0; vblk < 4; ++vblk) {
        const us* base = uvY + ((size_t)b * NLV + wave * 32 + vblk * 8) * NBN + n0;
        float s[8];
        #pragma unroll
        for (int j = 0; j < 8; ++j) {
            uint4 u = *(const uint4*)(base + (size_t)j * NBN);
            float acc = 0.f;
            auto term = [&](unsigned int uu, int k) {
                float d0 = fmaf(blo(uu), Yq[k],     1.f);
                float d1 = fmaf(bhi(uu), Yq[k + 1], 1.f);
                acc = fmaf(nw2[k],     __builtin_amdgcn_rcpf(d0), acc);
                acc = fmaf(nw2[k + 1], __builtin_amdgcn_rcpf(d1), acc);
            };
            term(u.x, 0); term(u.y, 2); term(u.z, 4); term(u.w, 6);
            s[j] = acc;
        }
        // uniform reduce over lane-bits 3,4,5 (ILP across 8 accumulators)
        #pragma unroll
        for (int m = 8; m <= 32; m <<= 1)
            #pragma unroll
            for (int j = 0; j < 8; ++j) s[j] += __shfl_xor(s[j], m);
        // reduce-scatter over lane-bits 0,1,2
        float t[4];
        #pragma unroll
        for (int p = 0; p < 4; ++p) {
            float ae = s[2*p]     + __shfl_xor(s[2*p],     1);
            float bo = s[2*p + 1] + __shfl_xor(s[2*p + 1], 1);
            t[p] = (lane & 1) ? bo : ae;
        }
        float u2[2];
        #pragma unroll
        for (int p = 0; p < 2; ++p) {
            float ae = t[2*p]     + __shfl_xor(t[2*p],     2);
            float bo = t[2*p + 1] + __shfl_xor(t[2*p + 1], 2);
            u2[p] = (lane & 2) ? bo : ae;
        }
        {
            float ae = u2[0] + __shfl_xor(u2[0], 4);
            float bo = u2[1] + __shfl_xor(u2[1], 4);
            float r  = (lane & 4) ? bo : ae;
            if (lane < 8) e_s[wave * 32 + vblk * 8 + lane] = sumw - r;
        }
    }
    __syncthreads();

    if (wave == 0) {
        float e0 = e_s[lane];
        float e1 = e_s[lane + 64];
        float m = fmaxf(e0, e1);
        #pragma unroll
        for (int off = 32; off; off >>= 1) m = fmaxf(m, __shfl_xor(m, off));
        float x0 = __builtin_amdgcn_exp2f((e0 - m) * LOG2E);
        float x1 = __builtin_amdgcn_exp2f((e1 - m) * LOG2E);
        float ss = x0 + x1;
        #pragma unroll
        for (int off = 32; off; off >>= 1) ss += __shfl_xor(ss, off);
        float inv = __builtin_amdgcn_rcpf(ss);
        float p0 = x0 * inv, p1 = x1 * inv;
        size_t o = (size_t)row * NLV;
        p_ws[o + lane]       = p0;
        p_ws[o + lane + 64]  = p1;
        out_w[o + lane]      = p0;
        out_w[o + lane + 64] = p1;
        out_e[o + lane]      = e0;
        out_e[o + lane + 64] = e1;
    }
}

// ---------------- aligned (bf16 vis) ----------------------------------------
// blk = qg*32 + b (qg: group of 4 q). Thread owns 4 f for 4 q.
__global__ __launch_bounds__(256) void aligned_k(
    const us* __restrict__ vis_b,     // [32,128,1024] bf16
    const float* __restrict__ p_ws,   // [2048,128]
    float* __restrict__ out_sgf)      // [32,64,1536]
{
    const int blk = blockIdx.x;
    const int b   = blk & 31;
    const int qg  = blk >> 5;         // 0..15
    const int tid = threadIdx.x;

    __shared__ float p_s[4][128];
    if (tid < 128) {
        const float* src = p_ws + (size_t)(b * NLQ + qg * 4) * NLV;
        ((float4*)&p_s[0][0])[tid] = ((const float4*)src)[tid];
    }
    __syncthreads();

    const int f0 = tid * 4;
    float4 acc[4] = {};
    const us* vb = vis_b + (size_t)b * NLV * NFS + f0;
    for (int v0 = 0; v0 < NLV; v0 += 4) {
        float4 pv[4];
        #pragma unroll
        for (int qq = 0; qq < 4; ++qq) pv[qq] = *(const float4*)&p_s[qq][v0];
        #pragma unroll
        for (int dv = 0; dv < 4; ++dv) {
            uint2 u = *(const uint2*)(vb + (size_t)(v0 + dv) * NFS);
            float x0 = blo(u.x), x1 = bhi(u.x), x2 = blo(u.y), x3 = bhi(u.y);
            #pragma unroll
            for (int qq = 0; qq < 4; ++qq) {
                float p = (dv == 0) ? pv[qq].x : (dv == 1) ? pv[qq].y
                        : (dv == 2) ? pv[qq].z : pv[qq].w;
                acc[qq].x = fmaf(p, x0, acc[qq].x);
                acc[qq].y = fmaf(p, x1, acc[qq].y);
                acc[qq].z = fmaf(p, x2, acc[qq].z);
                acc[qq].w = fmaf(p, x3, acc[qq].w);
            }
        }
    }
    #pragma unroll
    for (int qq = 0; qq < 4; ++qq) {
        size_t row = (size_t)(b * NLQ + qg * 4 + qq);
        *(float4*)(out_sgf + row * (NQS + NFS) + NQS + f0) = acc[qq];
    }
}

extern "C" void kernel_launch(void* const* d_in, const int* in_sizes, int n_in,
                              void* d_out, int out_size, void* d_ws, size_t ws_size,
                              hipStream_t stream) {
    const float* phr  = (const float*)d_in[0];
    const float* vis  = (const float*)d_in[1];
    const float* W    = (const float*)d_in[2];
    const float* U    = (const float*)d_in[3];
    const float* bias = (const float*)d_in[4];
    const float* wvec = (const float*)d_in[5];

    char* ws = (char*)d_ws;
    us* phr_b = (us*)ws;                                  // 2 MB
    us* vis_b = (us*)(ws + (2u << 20));                   // 8 MB
    us* W_b   = (us*)(ws + (10u << 20));                  // 0.5 MB
    us* U_b   = (us*)(ws + (10u << 20) + (512u << 10));   // 1 MB
    us* whY   = (us*)(ws + (12u << 20));                  // 2 MB
    us* uvY   = (us*)(ws + (14u << 20));                  // 4 MB
    float* p_ws = (float*)(ws + (18u << 20));             // 1 MB

    float* out     = (float*)d_out;
    float* out_sgf = out;
    float* out_w   = out_sgf + (size_t)NB * NLQ * (NQS + NFS);
    float* out_e   = out_w   + (size_t)NB * NLQ * NLV;

    convert_bf16<<<(TOT4 + 255) / 256, 256, 0, stream>>>(
        phr, vis, W, U, phr_b, vis_b, W_b, U_b, out_sgf);
    gemm_both<<<768, 256, 0, stream>>>(phr_b, W_b, bias, vis_b, U_b, whY, uvY);
    energize<<<NB * NLQ, 256, 0, stream>>>(whY, uvY, wvec, p_ws, out_w, out_e);
    aligned_k<<<NB * 16, 256, 0, stream>>>(vis_b, p_ws, out_sgf);
}